// Round 3
// baseline (270.988 us; speedup 1.0000x reference)
//
#include <hip/hip_runtime.h>

typedef unsigned short u16;
typedef __bf16 bf16x8 __attribute__((ext_vector_type(8)));
typedef float f32x4 __attribute__((ext_vector_type(4)));

// Problem constants (from reference)
#define NB 16      // batches
#define NC 64      // channels
#define NK 207     // nodes (K_DIM)
#define NL 64      // time (L_DIM)
#define KP 224     // padded GEMM K-dim over nodes (207 -> 224 = 7*32)
#define NKL 13248  // NK*NL
#define GROWS 1152 // stacked-G rows: 5*208 + 112 pad
#define CIN 320

__device__ __forceinline__ u16 f2bf(float f) {
  unsigned u = __builtin_bit_cast(unsigned, f);
  u += 0x7FFFu + ((u >> 16) & 1u);   // RNE; inputs are never NaN
  return (u16)(u >> 16);
}

// async global->LDS, 16 B per lane. ldst must be (wave-uniform base + lane*16).
__device__ __forceinline__ void g2l16(const u16* gsrc, u16* ldst) {
  __builtin_amdgcn_global_load_lds(
      (const __attribute__((address_space(1))) unsigned int*)gsrc,
      (__attribute__((address_space(3))) unsigned int*)ldst, 16, 0, 0);
}

// ---- prep, gather-style: no LDS, no barriers, no divisions in hot loops ----
// [0,1024)    : x -> xT[b][c*64+l][k] bf16 (k-padded to 224). Block=(b,c).
//               Thread: l=t&63, kq=t>>6; reads x[c][k][l] with lanes=l
//               (256B contiguous per instr); writes block-contiguous 28KB.
// [1024,1312) : A rows -> Abf + G q=1,3. 9 row-groups per (b,w); group 8
//               zero-fills Abf rows 224..255 (k_asq reads them).
// [1312,1536) : A columns -> AbfT (gather: lanes=n contiguous reads).
//               n=t covers 0..255 so rows 224..255 are zero-filled here.
// [1536,1568) : G q=0 identity
// 1568        : W -> bf16
__global__ __launch_bounds__(256) void k_prep(
    const float* __restrict__ x, const float* __restrict__ a0,
    const float* __restrict__ a1, const float* __restrict__ W,
    u16* __restrict__ xT, u16* __restrict__ Abf, u16* __restrict__ AbfT,
    u16* __restrict__ G, u16* __restrict__ Wbf) {
  int id = blockIdx.x, t = threadIdx.x;
  if (id < 1024) {
    int c = id & 63, b = id >> 6;
    const float* xc = x + (size_t)(b * 64 + c) * NKL;
    int l = t & 63, kq = t >> 6;
    u16* drow = xT + ((size_t)b * 4096 + c * 64 + l) * KP;
#pragma unroll
    for (int i = 0; i < 7; i++) {
      int kc = kq * 7 + i;
      u16 v[8] __attribute__((aligned(16)));
#pragma unroll
      for (int j = 0; j < 8; j++) {
        int k = kc * 8 + j;                       // wave-uniform guard
        v[j] = (k < NK) ? f2bf(xc[k * 64 + l]) : (u16)0;
      }
      *(int4*)(drow + kc * 8) = *(int4*)v;
    }
  } else if (id < 1312) {
    int local = id - 1024;
    int rt = local % 9, bw = local / 9;
    int b = bw >> 1, w = bw & 1;
    const float* A = (w ? a1 : a0) + (size_t)b * NK * NK;
    u16* Ab = Abf + (size_t)bw * 256 * KP;
    u16* Gq = G + ((size_t)b * GROWS + (1 + 2 * w) * 208) * KP;
    if (rt == 8) {                                // zero Abf rows 224..255
      int4 z = {0, 0, 0, 0};
      int4* p = (int4*)(Ab + (size_t)224 * KP);
      for (int ci = t; ci < 896; ci += 256) p[ci] = z;
    } else {
      int m0 = rt * 28;
      int kc = t & 31, rl = t >> 5;               // kc<28 active
      if (kc < 28) {
#pragma unroll
        for (int i = 0; i < 4; i++) {
          int ml = rl + 8 * i;
          if (ml < 28) {
            int m = m0 + ml;
            u16 v[8] __attribute__((aligned(16)));
#pragma unroll
            for (int j = 0; j < 8; j++) {
              int k = kc * 8 + j;
              v[j] = (m < NK && k < NK) ? f2bf(A[m * NK + k]) : (u16)0;
            }
            *(int4*)(Ab + (size_t)m * KP + kc * 8) = *(int4*)v;
            if (m < 208) *(int4*)(Gq + (size_t)m * KP + kc * 8) = *(int4*)v;
          }
        }
      }
    }
  } else if (id < 1536) {
    int local = id - 1312;
    int g = local % 7, bw = local / 7;
    int b = bw >> 1, w = bw & 1;
    const float* A = (w ? a1 : a0) + (size_t)b * NK * NK;
    u16* At = AbfT + (size_t)bw * 256 * KP;
    int n = t;                                    // 0..255 (224.. -> zeros)
#pragma unroll
    for (int mc4 = 0; mc4 < 4; mc4++) {
      int mc = g * 4 + mc4;
      u16 v[8] __attribute__((aligned(16)));
#pragma unroll
      for (int j = 0; j < 8; j++) {
        int m = mc * 8 + j;
        v[j] = (n < NK && m < NK) ? f2bf(A[m * NK + n]) : (u16)0;
      }
      *(int4*)(At + (size_t)n * KP + mc * 8) = *(int4*)v;
    }
  } else if (id < 1568) {
    int local = id - 1536, b = local >> 1, half = local & 1;
    for (int ci = t; ci < 104 * 28; ci += 256) {
      int jr = ci / 28, kc = ci - jr * 28;
      int j = half * 104 + jr;
      u16 v[8] __attribute__((aligned(16)));
      for (int jj = 0; jj < 8; jj++)
        v[jj] = (j == kc * 8 + jj && j < NK) ? (u16)0x3F80 : (u16)0;
      *(int4*)(G + ((size_t)b * GROWS + j) * KP + kc * 8) = *(int4*)v;
    }
  } else {
    for (int ci = t; ci < 2560; ci += 256) {
      u16 v[8] __attribute__((aligned(16)));
      for (int j = 0; j < 8; j++) v[j] = f2bf(W[ci * 8 + j]);
      *(int4*)(Wbf + ci * 8) = *(int4*)v;
    }
  }
}

// ---- prep: A^2 via MFMA -> G blocks q=2,4 ----------------------------------
__global__ void k_asq(const u16* __restrict__ Abf, const u16* __restrict__ AbfT,
                      u16* __restrict__ G) {
  int b = blockIdx.z >> 1, w = blockIdx.z & 1;
  int lane = threadIdx.x & 63, wave = threadIdx.x >> 6;
  int wm = wave >> 1, wn = wave & 1;
  const u16* Ab = Abf + ((size_t)b * 2 + w) * 256 * KP;
  const u16* At = AbfT + ((size_t)b * 2 + w) * 256 * KP;
  int m0 = blockIdx.y * 64 + wm * 32;
  int n0 = blockIdx.x * 64 + wn * 32;
  int r = lane & 15, q = lane >> 4;
  f32x4 acc[2][2] = {};
#pragma unroll
  for (int k0 = 0; k0 < KP; k0 += 32) {
    bf16x8 af[2], bg[2];
    for (int i = 0; i < 2; i++)
      af[i] = *(const bf16x8*)(Ab + (size_t)(m0 + i * 16 + r) * KP + k0 + q * 8);
    for (int i = 0; i < 2; i++)
      bg[i] = *(const bf16x8*)(At + (size_t)(n0 + i * 16 + r) * KP + k0 + q * 8);
    for (int i = 0; i < 2; i++)
      for (int j = 0; j < 2; j++)
        acc[i][j] = __builtin_amdgcn_mfma_f32_16x16x32_bf16(af[i], bg[j], acc[i][j], 0, 0, 0);
  }
  int qblk = 2 + 2 * w;
  for (int i = 0; i < 2; i++)
    for (int j = 0; j < 2; j++)
      for (int rr = 0; rr < 4; rr++) {
        int mj = m0 + i * 16 + q * 4 + rr;
        int nk = n0 + j * 16 + r;
        if (mj < 208 && nk < KP)
          G[((size_t)b * GROWS + qblk * 208 + mj) * KP + nk] = f2bf(acc[i][j][rr]);
      }
}

// ---- fused diffuse+conv, v3: A in registers, T aliases G, 3 blocks/CU ------
// Block = (b, jt of 16 nodes, lt of 4 l). 512 threads, 8 waves.
// GEMM-1: T_p[j,(t,c)] = sum_k G_p[j,k]*xT[c*64+lt*4+t, k]; A fragments are
//   wave-private -> loaded global->VGPR with depth-1 register prefetch
//   (compiler emits precise counted vmcnt); G staged once in LDS (35 KB);
//   NO barriers in the K-loop.
// T (46 KB) aliases the G region after one __syncthreads().
// GEMM-2: y = W @ T^T; W fragments prefetched to VGPRs across the barrier.
__global__ __launch_bounds__(512) void k_fused(
    const u16* __restrict__ G, const u16* __restrict__ xT,
    const u16* __restrict__ Wbf, const float* __restrict__ bias,
    float* __restrict__ y) {
  __shared__ __align__(16) u16 lds[23040];  // 46,080 B: G [0,17920) then T
  // bijective XCD swizzle: 3328 blocks, 416/XCD = 2 batches worth
  int id = blockIdx.x;
  int wg = (id & 7) * 416 + (id >> 3);
  int b = wg / 208, rem = wg % 208;
  int jt = rem >> 4, lt = rem & 15;
  int tid = threadIdx.x, wave = tid >> 6, lane = tid & 63;
  int r = lane & 15, q = lane >> 4;
  const u16* Gb = G + (size_t)b * GROWS * KP;

  // stage G: 35 fragment-major tiles (p*7+ks), 512 u16 each, loaded once
  for (int i2 = 0; i2 < 5; i2++) {
    int tile = i2 * 8 + wave;            // wave-uniform
    if (tile < 35) {
      int p = tile / 7, ks = tile - p * 7;
      g2l16(Gb + (size_t)(p * 208 + jt * 16 + r) * KP + ks * 32 + q * 8,
            &lds[tile * 512 + lane * 8]);
    }
  }
  // per-lane A-row pointers: m=(wave*2+mf)*16+r -> t=m>>6, c=m&63
  const u16* arow0;
  const u16* arow1;
  {
    int m0 = (wave * 2 + 0) * 16 + r, m1 = (wave * 2 + 1) * 16 + r;
    arow0 = xT + ((size_t)b * 4096 + (m0 & 63) * 64 + lt * 4 + (m0 >> 6)) * KP + q * 8;
    arow1 = xT + ((size_t)b * 4096 + (m1 & 63) * 64 + lt * 4 + (m1 >> 6)) * KP + q * 8;
  }
  bf16x8 afA0 = *(const bf16x8*)(arow0);
  bf16x8 afA1 = *(const bf16x8*)(arow1);
  asm volatile("s_waitcnt vmcnt(0)" ::: "memory");  // G staged (one-time drain)
  __builtin_amdgcn_s_barrier();                     // G visible to all waves

  f32x4 acc1[5][2] = {};
#pragma unroll
  for (int ks = 0; ks < 7; ks++) {
    bf16x8 afB0, afB1;
    if (ks < 6) {                       // register prefetch of next k-slice
      afB0 = *(const bf16x8*)(arow0 + (ks + 1) * 32);
      afB1 = *(const bf16x8*)(arow1 + (ks + 1) * 32);
    }
    __builtin_amdgcn_s_setprio(1);
#pragma unroll
    for (int p = 0; p < 5; p++) {
      bf16x8 bg = *(const bf16x8*)&lds[(p * 7 + ks) * 512 + lane * 8];
      acc1[p][0] = __builtin_amdgcn_mfma_f32_16x16x32_bf16(afA0, bg, acc1[p][0], 0, 0, 0);
      acc1[p][1] = __builtin_amdgcn_mfma_f32_16x16x32_bf16(afA1, bg, acc1[p][1], 0, 0, 0);
    }
    __builtin_amdgcn_s_setprio(0);
    afA0 = afB0; afA1 = afB1;
  }
  __syncthreads();   // all waves done reading G; reuse LDS region for T

  // write T[p][j][t][c] (stride 72 u16, 16B-aligned rows; c XOR-swizzle by j)
#pragma unroll
  for (int p = 0; p < 5; p++)
#pragma unroll
    for (int mf = 0; mf < 2; mf++) {
      int m = (wave * 2 + mf) * 16 + q * 4;
      int tt = m >> 6, c = m & 63;
      int cs = c ^ ((r & 7) << 3);
      int idxT = ((p * 16 + r) * 4 + tt) * 72 + cs;
      u16 v0 = f2bf(acc1[p][mf][0]), v1 = f2bf(acc1[p][mf][1]);
      u16 v2 = f2bf(acc1[p][mf][2]), v3 = f2bf(acc1[p][mf][3]);
      *(uint2*)&lds[idxT] = make_uint2((unsigned)v0 | ((unsigned)v1 << 16),
                                       (unsigned)v2 | ((unsigned)v3 << 16));
    }
  // prefetch all W fragments to VGPRs; they fly across the barrier
  int mo = wave >> 1, nh = (wave & 1) * 2;
  const u16* Wrow = Wbf + (size_t)(mo * 16 + r) * CIN + q * 8;
  bf16x8 aw[10];
#pragma unroll
  for (int ks = 0; ks < 10; ks++) aw[ks] = *(const bf16x8*)(Wrow + ks * 32);
  __syncthreads();

  // GEMM-2: y tile 64(o) x 64(j,t), K=320=(p,c). No barriers.
  f32x4 acc2[2] = {};
#pragma unroll
  for (int ks = 0; ks < 10; ks++) {
    int p = ks >> 1, c0 = (ks & 1) * 32;
#pragma unroll
    for (int nf = 0; nf < 2; nf++) {
      int n = (nh + nf) * 16 + r;
      int j = n >> 2, tt = n & 3;
      int cs = (c0 + q * 8) ^ ((j & 7) << 3);
      bf16x8 bt = *(const bf16x8*)&lds[((p * 16 + j) * 4 + tt) * 72 + cs];
      acc2[nf] = __builtin_amdgcn_mfma_f32_16x16x32_bf16(aw[ks], bt, acc2[nf], 0, 0, 0);
    }
  }

  // epilogue: per (o, j) the 4 t-values are 16B-contiguous in y
  int o0 = mo * 16 + q * 4;
  float4 bv = *(const float4*)&bias[o0];
  float* yb = y + (size_t)b * 64 * NKL;
#pragma unroll
  for (int nf = 0; nf < 2; nf++) {
    int n = (nh + nf) * 16 + r;
    int j = n >> 2, tt = n & 3;
    int jnode = jt * 16 + j;
    if (jnode < NK) {
      int col = jnode * 64 + lt * 4 + tt;
      yb[(size_t)(o0 + 0) * NKL + col] = acc2[nf][0] + bv.x;
      yb[(size_t)(o0 + 1) * NKL + col] = acc2[nf][1] + bv.y;
      yb[(size_t)(o0 + 2) * NKL + col] = acc2[nf][2] + bv.z;
      yb[(size_t)(o0 + 3) * NKL + col] = acc2[nf][3] + bv.w;
    }
  }
}

extern "C" void kernel_launch(void* const* d_in, const int* in_sizes, int n_in,
                              void* d_out, int out_size, void* d_ws, size_t ws_size,
                              hipStream_t stream) {
  const float* x = (const float*)d_in[0];
  const float* a0 = (const float*)d_in[1];
  const float* a1 = (const float*)d_in[2];
  const float* W = (const float*)d_in[3];
  const float* bias = (const float*)d_in[4];
  float* y = (float*)d_out;
  char* ws = (char*)d_ws;

  size_t off = 0;
  auto alloc = [&](size_t bytes) {
    size_t o = off;
    off = (off + bytes + 511) & ~(size_t)511;
    return o;
  };
  size_t o_xT  = alloc((size_t)NB * 4096 * KP * 2);
  size_t o_G   = alloc((size_t)NB * GROWS * KP * 2);
  size_t o_Ab  = alloc((size_t)NB * 2 * 256 * KP * 2);
  size_t o_At  = alloc((size_t)NB * 2 * 256 * KP * 2);
  size_t o_Wb  = alloc((size_t)64 * CIN * 2);
  (void)ws_size;

  u16* xT  = (u16*)(ws + o_xT);
  u16* G   = (u16*)(ws + o_G);
  u16* Abf = (u16*)(ws + o_Ab);
  u16* AbfT= (u16*)(ws + o_At);
  u16* Wbf = (u16*)(ws + o_Wb);

  k_prep<<<dim3(1569), 256, 0, stream>>>(x, a0, a1, W, xT, Abf, AbfT, G, Wbf);
  k_asq<<<dim3(4, 4, 32), 256, 0, stream>>>(Abf, AbfT, G);
  k_fused<<<dim3(16 * 13 * 16), 512, 0, stream>>>(G, xT, Wbf, bias, y);
}

// Round 4
// 202.001 us; speedup vs baseline: 1.3415x; 1.3415x over previous
//
#include <hip/hip_runtime.h>

typedef unsigned short u16;
typedef __bf16 bf16x8 __attribute__((ext_vector_type(8)));
typedef float f32x4 __attribute__((ext_vector_type(4)));

// Problem constants (from reference)
#define NB 16      // batches
#define NC 64      // channels
#define NK 207     // nodes (K_DIM)
#define NL 64      // time (L_DIM)
#define KP 224     // padded GEMM K-dim over nodes (207 -> 224 = 7*32)
#define NKL 13248  // NK*NL
#define CIN 320

// Fragment-major layouts: one MFMA A/B operand tile (16 rows x 32 k, bf16)
// = 512 contiguous u16 = 1 KB. Element (row r16, k=ks*32+q*8+e) lives at
// tile*512 + (r16 + 16*q)*8 + e. All GEMM staging reads become contiguous
// 1 KB bursts (vs 16 scattered 64B lines with row-major).
//   Xf [b][tile=l*4+(c>>4)][ks]  tile<256, ks<7   (row = l*64+c, k = node)
//   Gf [b][p][jt][ks]            p<5, jt<13, ks<7 (row = j, k = node)
//   Af [bw][tile][ks]            tile<16, ks<7    (row = m, k = node)
//   Atf[bw][tile][ks]            tile<16, ks<7    (row = n, k = m)
//   Wf [ot][ks]                  ot<4, ks<10      (row = o, k = cin)

__device__ __forceinline__ u16 f2bf(float f) {
  unsigned u = __builtin_bit_cast(unsigned, f);
  u += 0x7FFFu + ((u >> 16) & 1u);   // RNE; inputs are never NaN
  return (u16)(u >> 16);
}

// async global->LDS, 16 B per lane. ldst must be (wave-uniform base + lane*16).
__device__ __forceinline__ void g2l16(const u16* gsrc, u16* ldst) {
  __builtin_amdgcn_global_load_lds(
      (const __attribute__((address_space(1))) unsigned int*)gsrc,
      (__attribute__((address_space(3))) unsigned int*)ldst, 16, 0, 0);
}

// ---- prep ------------------------------------------------------------------
// [0,1024)    : x -> Xf. Block=(b,c). Two k-chunks of 112 staged as
//               lds[k][l] (65-pad): float4-coalesced loads, conflict-free
//               lane-consecutive reads, fragment-major int4 writes.
// [1024,1312) : A rows -> Af + Gf p=1,3 (9 groups per bw; group 8 zeros
//               Af tiles 14,15 = rows 224..255).
// [1312,1536) : A cols -> Atf (lanes=n contiguous reads; n=t covers 0..255).
// [1536,1568) : Gf p=0 identity.
// 1568        : W -> Wf.
__global__ __launch_bounds__(256) void k_prep(
    const float* __restrict__ x, const float* __restrict__ a0,
    const float* __restrict__ a1, const float* __restrict__ W,
    u16* __restrict__ Xf, u16* __restrict__ Af, u16* __restrict__ Atf,
    u16* __restrict__ Gf, u16* __restrict__ Wbf) {
  __shared__ float lds[112 * 65];   // 29,120 B
  int id = blockIdx.x, t = threadIdx.x;
  if (id < 1024) {
    int c = id & 63, b = id >> 6;
    const float4* xp4 = (const float4*)(x + (size_t)(b * 64 + c) * NKL);
    u16* Xb = Xf + (size_t)b * 256 * 7 * 512;
    int cl = c & 15, c4 = c >> 4;
    for (int h = 0; h < 2; h++) {
      for (int i4 = t; i4 < 1792; i4 += 256) {       // 112 k x 16 float4
        int kk = i4 >> 4, l0 = (i4 & 15) * 4;
        int k = h * 112 + kk;
        float4 v = {0.f, 0.f, 0.f, 0.f};
        if (k < NK) v = xp4[(size_t)k * 16 + (l0 >> 2)];
        lds[kk * 65 + l0 + 0] = v.x;
        lds[kk * 65 + l0 + 1] = v.y;
        lds[kk * 65 + l0 + 2] = v.z;
        lds[kk * 65 + l0 + 3] = v.w;
      }
      __syncthreads();
      for (int idx = t; idx < 896; idx += 256) {     // 64 l x 14 kc
        int l = idx & 63, kcl = idx >> 6;
        int kc = h * 14 + kcl;
        u16 v[8] __attribute__((aligned(16)));
#pragma unroll
        for (int j = 0; j < 8; j++) v[j] = f2bf(lds[(kcl * 8 + j) * 65 + l]);
        size_t addr = ((size_t)(l * 4 + c4) * 7 + (kc >> 2)) * 512 +
                      (cl + 16 * (kc & 3)) * 8;
        *(int4*)(Xb + addr) = *(int4*)v;
      }
      __syncthreads();
    }
  } else if (id < 1312) {
    int local = id - 1024;
    int rt = local % 9, bw = local / 9;
    int b = bw >> 1, w = bw & 1;
    const float* A = (w ? a1 : a0) + (size_t)b * NK * NK;
    u16* Ab = Af + (size_t)bw * 16 * 7 * 512;
    u16* Gp = Gf + ((size_t)b * 5 + (1 + 2 * w)) * 13 * 7 * 512;
    if (rt == 8) {                                   // zero Af tiles 14,15
      int4 z = {0, 0, 0, 0};
      int4* p = (int4*)(Ab + (size_t)14 * 7 * 512);
      for (int ci = t; ci < 896; ci += 256) p[ci] = z;
    } else {
      int m0 = rt * 28;
      int kc = t & 31, rl = t >> 5;                  // kc<28 active
      if (kc < 28) {
#pragma unroll
        for (int i = 0; i < 4; i++) {
          int ml = rl + 8 * i;
          if (ml < 28) {
            int m = m0 + ml;                         // < 224
            u16 v[8] __attribute__((aligned(16)));
#pragma unroll
            for (int j = 0; j < 8; j++) {
              int k = kc * 8 + j;
              v[j] = (m < NK && k < NK) ? f2bf(A[m * NK + k]) : (u16)0;
            }
            size_t fo = ((size_t)(m >> 4) * 7 + (kc >> 2)) * 512 +
                        ((m & 15) + 16 * (kc & 3)) * 8;
            *(int4*)(Ab + fo) = *(int4*)v;
            if (m < 208) *(int4*)(Gp + fo) = *(int4*)v;
          }
        }
      }
    }
  } else if (id < 1536) {
    int local = id - 1312;
    int g = local % 7, bw = local / 7;
    int b = bw >> 1, w = bw & 1;
    const float* A = (w ? a1 : a0) + (size_t)b * NK * NK;
    u16* At = Atf + (size_t)bw * 16 * 7 * 512;
    int n = t;                                       // 0..255 (224.. -> zeros)
#pragma unroll
    for (int mc4 = 0; mc4 < 4; mc4++) {
      int mc = g * 4 + mc4;
      u16 v[8] __attribute__((aligned(16)));
#pragma unroll
      for (int j = 0; j < 8; j++) {
        int m = mc * 8 + j;
        v[j] = (n < NK && m < NK) ? f2bf(A[m * NK + n]) : (u16)0;
      }
      *(int4*)(At + ((size_t)(n >> 4) * 7 + (mc >> 2)) * 512 +
               ((n & 15) + 16 * (mc & 3)) * 8) = *(int4*)v;
    }
  } else if (id < 1568) {
    int local = id - 1536, b = local >> 1, half = local & 1;
    u16* Gp = Gf + (size_t)b * 5 * 13 * 7 * 512;     // p = 0
    for (int ci = t; ci < 104 * 28; ci += 256) {
      int jr = ci / 28, kc = ci - jr * 28;
      int j = half * 104 + jr;
      u16 v[8] __attribute__((aligned(16)));
      for (int jj = 0; jj < 8; jj++)
        v[jj] = (j == kc * 8 + jj && j < NK) ? (u16)0x3F80 : (u16)0;
      *(int4*)(Gp + ((size_t)(j >> 4) * 7 + (kc >> 2)) * 512 +
               ((j & 15) + 16 * (kc & 3)) * 8) = *(int4*)v;
    }
  } else {
    for (int ci = t; ci < 2560; ci += 256) {
      int o = ci / 40, kc = ci - o * 40;
      u16 v[8] __attribute__((aligned(16)));
      for (int j = 0; j < 8; j++) v[j] = f2bf(W[o * CIN + kc * 8 + j]);
      *(int4*)(Wbf + ((size_t)(o >> 4) * 10 + (kc >> 2)) * 512 +
               ((o & 15) + 16 * (kc & 3)) * 8) = *(int4*)v;
    }
  }
}

// ---- prep: A^2 via MFMA -> Gf p=2,4 (fragment-contiguous operand reads) ----
__global__ __launch_bounds__(256) void k_asq(
    const u16* __restrict__ Af, const u16* __restrict__ Atf,
    u16* __restrict__ Gf) {
  int b = blockIdx.z >> 1, w = blockIdx.z & 1;
  int lane = threadIdx.x & 63, wave = threadIdx.x >> 6;
  int wm = wave >> 1, wn = wave & 1;
  const u16* Ab = Af + ((size_t)b * 2 + w) * 16 * 7 * 512;
  const u16* At = Atf + ((size_t)b * 2 + w) * 16 * 7 * 512;
  int m0 = blockIdx.y * 64 + wm * 32;
  int n0 = blockIdx.x * 64 + wn * 32;
  int r = lane & 15, q = lane >> 4;
  f32x4 acc[2][2] = {};
#pragma unroll
  for (int ks = 0; ks < 7; ks++) {
    bf16x8 af[2], bg[2];
    for (int i = 0; i < 2; i++)
      af[i] = *(const bf16x8*)(Ab + ((size_t)((m0 >> 4) + i) * 7 + ks) * 512 + lane * 8);
    for (int i = 0; i < 2; i++)
      bg[i] = *(const bf16x8*)(At + ((size_t)((n0 >> 4) + i) * 7 + ks) * 512 + lane * 8);
    for (int i = 0; i < 2; i++)
      for (int j = 0; j < 2; j++)
        acc[i][j] = __builtin_amdgcn_mfma_f32_16x16x32_bf16(af[i], bg[j], acc[i][j], 0, 0, 0);
  }
  int qblk = 2 + 2 * w;
  u16* Gp = Gf + ((size_t)b * 5 + qblk) * 13 * 7 * 512;
  for (int i = 0; i < 2; i++)
    for (int j = 0; j < 2; j++)
      for (int rr = 0; rr < 4; rr++) {
        int mj = m0 + i * 16 + q * 4 + rr;
        int nk = n0 + j * 16 + r;
        if (mj < 208 && nk < KP)
          Gp[((size_t)(mj >> 4) * 7 + (nk >> 5)) * 512 +
             ((mj & 15) + 16 * ((nk >> 3) & 3)) * 8 + (nk & 7)] = f2bf(acc[i][j][rr]);
      }
}

// ---- fused diffuse+conv, v4: round-2 DMA discipline + fragment-major src ---
// Block = (b, jt of 16 nodes, lt of 4 l). 512 threads, 8 waves.
// GEMM-1: T_p[j,(t,c)] = sum_k G_p[j,k]*x[(c,lt*4+t),k]. G pre-staged (35 KB,
//   contiguous 1KB DMAs); A double-buffered wave-private DMA, vmcnt(2),
//   NO barriers in K-loop. All staging sources are fragment-contiguous.
// T (46 KB) aliases the G+A region after __syncthreads().
// GEMM-2: y = W @ T^T; Wf fragments prefetched to VGPRs across the barrier.
#define AG 17920            // A-stage base (u16); G region is [0, 17920)
__global__ __launch_bounds__(512, 4) void k_fused(
    const u16* __restrict__ Gf, const u16* __restrict__ Xf,
    const u16* __restrict__ Wbf, const float* __restrict__ bias,
    float* __restrict__ y) {
  __shared__ __align__(16) u16 lds[AG + 2 * 8192];  // 68,608 B -> 2 blocks/CU
  // bijective XCD swizzle: 3328 blocks, 416/XCD = 2 batches worth
  int id = blockIdx.x;
  int wg = (id & 7) * 416 + (id >> 3);
  int b = wg / 208, rem = wg % 208;
  int jt = rem >> 4, lt = rem & 15;
  int tid = threadIdx.x, wave = tid >> 6, lane = tid & 63;
  int r = lane & 15, q = lane >> 4;
  const u16* Gb = Gf + (size_t)b * 5 * 13 * 7 * 512;
  const u16* Xw = Xf + ((size_t)b * 256 + lt * 16) * 7 * 512;  // 16 tiles

  // stage G: 35 fragment tiles (p*7+ks), each one contiguous 1 KB DMA
  for (int i2 = 0; i2 < 5; i2++) {
    int tile = i2 * 8 + wave;            // wave-uniform
    if (tile < 35) {
      int p = tile / 7, ks = tile - p * 7;
      g2l16(Gb + ((size_t)(p * 13 + jt) * 7 + ks) * 512 + lane * 8,
            &lds[tile * 512 + lane * 8]);
    }
  }
  // prologue: stage ks=0 into buf0 (wave-private tiles wave*2+{0,1})
  for (int i2 = 0; i2 < 2; i2++) {
    int tl = wave * 2 + i2;
    g2l16(Xw + (size_t)tl * 7 * 512 + lane * 8, &lds[AG + tl * 512 + lane * 8]);
  }
  asm volatile("s_waitcnt vmcnt(2)" ::: "memory");  // G landed; stage0 in flight
  __builtin_amdgcn_s_barrier();                     // G visible to all waves

  f32x4 acc1[5][2] = {};
#pragma unroll
  for (int ks = 0; ks < 7; ks++) {
    int cur = ks & 1;
    if (ks < 6) {                      // stage ks+1 into other buffer
      for (int i2 = 0; i2 < 2; i2++) {
        int tl = wave * 2 + i2;
        g2l16(Xw + ((size_t)tl * 7 + ks + 1) * 512 + lane * 8,
              &lds[AG + (cur ^ 1) * 8192 + tl * 512 + lane * 8]);
      }
      asm volatile("s_waitcnt vmcnt(2)" ::: "memory");  // buf[cur] ready (mine)
    } else {
      asm volatile("s_waitcnt vmcnt(0)" ::: "memory");
    }
    bf16x8 af0 = *(const bf16x8*)&lds[AG + cur * 8192 + (wave * 2 + 0) * 512 + lane * 8];
    bf16x8 af1 = *(const bf16x8*)&lds[AG + cur * 8192 + (wave * 2 + 1) * 512 + lane * 8];
    __builtin_amdgcn_s_setprio(1);
#pragma unroll
    for (int p = 0; p < 5; p++) {
      bf16x8 bg = *(const bf16x8*)&lds[(p * 7 + ks) * 512 + lane * 8];
      acc1[p][0] = __builtin_amdgcn_mfma_f32_16x16x32_bf16(af0, bg, acc1[p][0], 0, 0, 0);
      acc1[p][1] = __builtin_amdgcn_mfma_f32_16x16x32_bf16(af1, bg, acc1[p][1], 0, 0, 0);
    }
    __builtin_amdgcn_s_setprio(0);
  }
  __syncthreads();   // all waves done with G + A-stage; reuse LDS for T

  // write T[p][j][t][c] (stride 72 u16, 16B-aligned rows; c XOR-swizzle by j)
#pragma unroll
  for (int p = 0; p < 5; p++)
#pragma unroll
    for (int mf = 0; mf < 2; mf++) {
      int m = (wave * 2 + mf) * 16 + q * 4;
      int tt = m >> 6, c = m & 63;
      int cs = c ^ ((r & 7) << 3);
      int idxT = ((p * 16 + r) * 4 + tt) * 72 + cs;
      u16 v0 = f2bf(acc1[p][mf][0]), v1 = f2bf(acc1[p][mf][1]);
      u16 v2 = f2bf(acc1[p][mf][2]), v3 = f2bf(acc1[p][mf][3]);
      *(uint2*)&lds[idxT] = make_uint2((unsigned)v0 | ((unsigned)v1 << 16),
                                       (unsigned)v2 | ((unsigned)v3 << 16));
    }
  // prefetch all W fragments to VGPRs (contiguous from Wf); fly across barrier
  int mo = wave >> 1, nh = (wave & 1) * 2;
  const u16* Wt = Wbf + (size_t)mo * 10 * 512 + lane * 8;
  bf16x8 aw[10];
#pragma unroll
  for (int ks = 0; ks < 10; ks++) aw[ks] = *(const bf16x8*)(Wt + ks * 512);
  __syncthreads();

  // GEMM-2: y tile 64(o) x 64(j,t), K=320=(p,c). No barriers.
  f32x4 acc2[2] = {};
#pragma unroll
  for (int ks = 0; ks < 10; ks++) {
    int p = ks >> 1, c0 = (ks & 1) * 32;
#pragma unroll
    for (int nf = 0; nf < 2; nf++) {
      int n = (nh + nf) * 16 + r;
      int j = n >> 2, tt = n & 3;
      int cs = (c0 + q * 8) ^ ((j & 7) << 3);
      bf16x8 bt = *(const bf16x8*)&lds[((p * 16 + j) * 4 + tt) * 72 + cs];
      acc2[nf] = __builtin_amdgcn_mfma_f32_16x16x32_bf16(aw[ks], bt, acc2[nf], 0, 0, 0);
    }
  }

  // epilogue: per (o, j) the 4 t-values are 16B-contiguous in y
  int o0 = mo * 16 + q * 4;
  float4 bv = *(const float4*)&bias[o0];
  float* yb = y + (size_t)b * 64 * NKL;
#pragma unroll
  for (int nf = 0; nf < 2; nf++) {
    int n = (nh + nf) * 16 + r;
    int j = n >> 2, tt = n & 3;
    int jnode = jt * 16 + j;
    if (jnode < NK) {
      int col = jnode * 64 + lt * 4 + tt;
      yb[(size_t)(o0 + 0) * NKL + col] = acc2[nf][0] + bv.x;
      yb[(size_t)(o0 + 1) * NKL + col] = acc2[nf][1] + bv.y;
      yb[(size_t)(o0 + 2) * NKL + col] = acc2[nf][2] + bv.z;
      yb[(size_t)(o0 + 3) * NKL + col] = acc2[nf][3] + bv.w;
    }
  }
}

extern "C" void kernel_launch(void* const* d_in, const int* in_sizes, int n_in,
                              void* d_out, int out_size, void* d_ws, size_t ws_size,
                              hipStream_t stream) {
  const float* x = (const float*)d_in[0];
  const float* a0 = (const float*)d_in[1];
  const float* a1 = (const float*)d_in[2];
  const float* W = (const float*)d_in[3];
  const float* bias = (const float*)d_in[4];
  float* y = (float*)d_out;
  char* ws = (char*)d_ws;

  size_t off = 0;
  auto alloc = [&](size_t bytes) {
    size_t o = off;
    off = (off + bytes + 511) & ~(size_t)511;
    return o;
  };
  size_t o_Xf = alloc((size_t)NB * 256 * 7 * 512 * 2);       // 29.4 MB
  size_t o_Gf = alloc((size_t)NB * 5 * 13 * 7 * 512 * 2);    // 7.5 MB
  size_t o_Af = alloc((size_t)NB * 2 * 16 * 7 * 512 * 2);    // 3.7 MB
  size_t o_At = alloc((size_t)NB * 2 * 16 * 7 * 512 * 2);    // 3.7 MB
  size_t o_Wf = alloc((size_t)4 * 10 * 512 * 2);             // 40 KB
  (void)ws_size;

  u16* Xf  = (u16*)(ws + o_Xf);
  u16* Gf  = (u16*)(ws + o_Gf);
  u16* Af  = (u16*)(ws + o_Af);
  u16* Atf = (u16*)(ws + o_At);
  u16* Wf  = (u16*)(ws + o_Wf);

  k_prep<<<dim3(1569), 256, 0, stream>>>(x, a0, a1, W, Xf, Af, Atf, Gf, Wf);
  k_asq<<<dim3(4, 4, 32), 256, 0, stream>>>(Af, Atf, Gf);
  k_fused<<<dim3(16 * 13 * 16), 512, 0, stream>>>(Gf, Xf, Wf, bias, y);
}

// Round 5
// 189.413 us; speedup vs baseline: 1.4307x; 1.0665x over previous
//
#include <hip/hip_runtime.h>

typedef unsigned short u16;
typedef __bf16 bf16x8 __attribute__((ext_vector_type(8)));
typedef float f32x4 __attribute__((ext_vector_type(4)));

// Problem constants (from reference)
#define NB 16      // batches
#define NC 64      // channels
#define NK 207     // nodes (K_DIM)
#define NL 64      // time (L_DIM)
#define KP 224     // padded GEMM K-dim over nodes (207 -> 224 = 7*32)
#define NKL 13248  // NK*NL
#define CIN 320

// Fragment-major layouts: one MFMA A/B operand tile (16 rows x 32 k, bf16)
// = 512 contiguous u16 = 1 KB. Element (row r16, k=ks*32+q*8+e) lives at
// tile*512 + (r16 + 16*q)*8 + e.
//   Xf [b][tile=l*4+(c>>4)][ks]  tile<256, ks<7   (row = l*64+c, k = node)
//   Gf [b][p][jt][ks]            p<5, jt<13, ks<7 (row = j, k = node)
//   Af [bw][tile][ks]            tile<16, ks<7    (row = m, k = node)
//   Atf[bw][tile][ks]            tile<16, ks<7    (row = n, k = m)
//   Wf [ot][ks]                  ot<4, ks<10      (row = o, k = cin)

__device__ __forceinline__ u16 f2bf(float f) {
  unsigned u = __builtin_bit_cast(unsigned, f);
  u += 0x7FFFu + ((u >> 16) & 1u);   // RNE; inputs are never NaN
  return (u16)(u >> 16);
}

// async global->LDS, 16 B per lane. ldst must be (wave-uniform base + lane*16).
__device__ __forceinline__ void g2l16(const u16* gsrc, u16* ldst) {
  __builtin_amdgcn_global_load_lds(
      (const __attribute__((address_space(1))) unsigned int*)gsrc,
      (__attribute__((address_space(3))) unsigned int*)ldst, 16, 0, 0);
}

// ---- prep ------------------------------------------------------------------
// [0,512)     : x -> Xf. Block=(b, c4, lh, ksh): 16 channels, 16 l, 3-4 ks.
//               Phase A: lane = consecutive k, reads one FULL 64B line
//               (16 l fp32) per (c,k); scalar bf16 scatter into
//               fragment-shaped LDS xs[ll][ksl][frag 512].
//               Phase B: wave-contiguous b128 LDS read + 1KB-contiguous
//               global fragment store. Both global sides line-granular.
// [512,800)   : A rows -> Af + Gf p=1,3 (9 groups/bw; group 8 zeros tiles 14,15)
// [800,1024)  : A cols -> Atf (lanes=n contiguous reads)
// [1024,1056) : Gf p=0 identity
// 1056        : W -> Wf
__global__ __launch_bounds__(256) void k_prep(
    const float* __restrict__ x, const float* __restrict__ a0,
    const float* __restrict__ a1, const float* __restrict__ W,
    u16* __restrict__ Xf, u16* __restrict__ Af, u16* __restrict__ Atf,
    u16* __restrict__ Gf, u16* __restrict__ Wbf) {
  __shared__ __align__(16) u16 xs[16 * 2048];   // 64 KB: [ll][ksl(4)][512]
  int id = blockIdx.x, t = threadIdx.x;
  if (id < 512) {
    int b = id >> 5, rem = id & 31;
    int c4 = rem >> 3, lh = (rem >> 1) & 3, ksh = rem & 1;
    int ks0 = ksh ? 4 : 0, nks = ksh ? 3 : 4;
    int kw = nks * 32;                 // 128 or 96
    int l0 = lh * 16;
    int cl = t >> 4, kl = t & 15;
    const float* xc = x + (size_t)(b * 64 + c4 * 16 + cl) * NKL;
    // phase A: per (c,k) read full 64B line (16 l), convert, scatter to LDS
    for (int kk = kl; kk < kw; kk += 16) {
      int k = ksh * 128 + kk;
      float4 v0 = {0.f, 0.f, 0.f, 0.f}, v1 = v0, v2 = v0, v3 = v0;
      if (k < NK) {
        const float4* p = (const float4*)(xc + (size_t)k * 64 + l0);
        v0 = p[0]; v1 = p[1]; v2 = p[2]; v3 = p[3];
      }
      int ksl = kk >> 5, q = (kk >> 3) & 3, e = kk & 7;
      u16* dst = &xs[ksl * 512 + (cl + 16 * q) * 8 + e];   // +ll*2048
      dst[0 * 2048] = f2bf(v0.x);  dst[1 * 2048] = f2bf(v0.y);
      dst[2 * 2048] = f2bf(v0.z);  dst[3 * 2048] = f2bf(v0.w);
      dst[4 * 2048] = f2bf(v1.x);  dst[5 * 2048] = f2bf(v1.y);
      dst[6 * 2048] = f2bf(v1.z);  dst[7 * 2048] = f2bf(v1.w);
      dst[8 * 2048] = f2bf(v2.x);  dst[9 * 2048] = f2bf(v2.y);
      dst[10 * 2048] = f2bf(v2.z); dst[11 * 2048] = f2bf(v2.w);
      dst[12 * 2048] = f2bf(v3.x); dst[13 * 2048] = f2bf(v3.y);
      dst[14 * 2048] = f2bf(v3.z); dst[15 * 2048] = f2bf(v3.w);
    }
    __syncthreads();
    // phase B: each wave stores whole 1KB fragments, contiguous both sides
    int wavei = t >> 6, lane = t & 63;
    u16* Xb = Xf + (size_t)b * 256 * 7 * 512;
    for (int ll = wavei; ll < 16; ll += 4) {
      int l = l0 + ll;
      for (int ksl = 0; ksl < nks; ksl++) {
        bf16x8 v = *(const bf16x8*)&xs[ll * 2048 + ksl * 512 + lane * 8];
        *(bf16x8*)(Xb + ((size_t)(l * 4 + c4) * 7 + ks0 + ksl) * 512 +
                   lane * 8) = v;
      }
    }
  } else if (id < 800) {
    int local = id - 512;
    int rt = local % 9, bw = local / 9;
    int b = bw >> 1, w = bw & 1;
    const float* A = (w ? a1 : a0) + (size_t)b * NK * NK;
    u16* Ab = Af + (size_t)bw * 16 * 7 * 512;
    u16* Gp = Gf + ((size_t)b * 5 + (1 + 2 * w)) * 13 * 7 * 512;
    if (rt == 8) {                                   // zero Af tiles 14,15
      int4 z = {0, 0, 0, 0};
      int4* p = (int4*)(Ab + (size_t)14 * 7 * 512);
      for (int ci = t; ci < 896; ci += 256) p[ci] = z;
    } else {
      int m0 = rt * 28;
      int kc = t & 31, rl = t >> 5;                  // kc<28 active
      if (kc < 28) {
#pragma unroll
        for (int i = 0; i < 4; i++) {
          int ml = rl + 8 * i;
          if (ml < 28) {
            int m = m0 + ml;                         // < 224
            u16 v[8] __attribute__((aligned(16)));
#pragma unroll
            for (int j = 0; j < 8; j++) {
              int k = kc * 8 + j;
              v[j] = (m < NK && k < NK) ? f2bf(A[m * NK + k]) : (u16)0;
            }
            size_t fo = ((size_t)(m >> 4) * 7 + (kc >> 2)) * 512 +
                        ((m & 15) + 16 * (kc & 3)) * 8;
            *(int4*)(Ab + fo) = *(int4*)v;
            if (m < 208) *(int4*)(Gp + fo) = *(int4*)v;
          }
        }
      }
    }
  } else if (id < 1024) {
    int local = id - 800;
    int g = local % 7, bw = local / 7;
    int b = bw >> 1, w = bw & 1;
    const float* A = (w ? a1 : a0) + (size_t)b * NK * NK;
    u16* At = Atf + (size_t)bw * 16 * 7 * 512;
    int n = t;                                       // 0..255 (224.. -> zeros)
#pragma unroll
    for (int mc4 = 0; mc4 < 4; mc4++) {
      int mc = g * 4 + mc4;
      u16 v[8] __attribute__((aligned(16)));
#pragma unroll
      for (int j = 0; j < 8; j++) {
        int m = mc * 8 + j;
        v[j] = (n < NK && m < NK) ? f2bf(A[m * NK + n]) : (u16)0;
      }
      *(int4*)(At + ((size_t)(n >> 4) * 7 + (mc >> 2)) * 512 +
               ((n & 15) + 16 * (mc & 3)) * 8) = *(int4*)v;
    }
  } else if (id < 1056) {
    int local = id - 1024, b = local >> 1, half = local & 1;
    u16* Gp = Gf + (size_t)b * 5 * 13 * 7 * 512;     // p = 0
    for (int ci = t; ci < 104 * 28; ci += 256) {
      int jr = ci / 28, kc = ci - jr * 28;
      int j = half * 104 + jr;
      u16 v[8] __attribute__((aligned(16)));
      for (int jj = 0; jj < 8; jj++)
        v[jj] = (j == kc * 8 + jj && j < NK) ? (u16)0x3F80 : (u16)0;
      *(int4*)(Gp + ((size_t)(j >> 4) * 7 + (kc >> 2)) * 512 +
               ((j & 15) + 16 * (kc & 3)) * 8) = *(int4*)v;
    }
  } else {
    for (int ci = t; ci < 2560; ci += 256) {
      int o = ci / 40, kc = ci - o * 40;
      u16 v[8] __attribute__((aligned(16)));
      for (int j = 0; j < 8; j++) v[j] = f2bf(W[o * CIN + kc * 8 + j]);
      *(int4*)(Wbf + ((size_t)(o >> 4) * 10 + (kc >> 2)) * 512 +
               ((o & 15) + 16 * (kc & 3)) * 8) = *(int4*)v;
    }
  }
}

// ---- prep: A^2 via MFMA -> Gf p=2,4 (fragment-contiguous operand reads) ----
__global__ __launch_bounds__(256) void k_asq(
    const u16* __restrict__ Af, const u16* __restrict__ Atf,
    u16* __restrict__ Gf) {
  int b = blockIdx.z >> 1, w = blockIdx.z & 1;
  int lane = threadIdx.x & 63, wave = threadIdx.x >> 6;
  int wm = wave >> 1, wn = wave & 1;
  const u16* Ab = Af + ((size_t)b * 2 + w) * 16 * 7 * 512;
  const u16* At = Atf + ((size_t)b * 2 + w) * 16 * 7 * 512;
  int m0 = blockIdx.y * 64 + wm * 32;
  int n0 = blockIdx.x * 64 + wn * 32;
  int r = lane & 15, q = lane >> 4;
  f32x4 acc[2][2] = {};
#pragma unroll
  for (int ks = 0; ks < 7; ks++) {
    bf16x8 af[2], bg[2];
    for (int i = 0; i < 2; i++)
      af[i] = *(const bf16x8*)(Ab + ((size_t)((m0 >> 4) + i) * 7 + ks) * 512 + lane * 8);
    for (int i = 0; i < 2; i++)
      bg[i] = *(const bf16x8*)(At + ((size_t)((n0 >> 4) + i) * 7 + ks) * 512 + lane * 8);
    for (int i = 0; i < 2; i++)
      for (int j = 0; j < 2; j++)
        acc[i][j] = __builtin_amdgcn_mfma_f32_16x16x32_bf16(af[i], bg[j], acc[i][j], 0, 0, 0);
  }
  int qblk = 2 + 2 * w;
  u16* Gp = Gf + ((size_t)b * 5 + qblk) * 13 * 7 * 512;
  for (int i = 0; i < 2; i++)
    for (int j = 0; j < 2; j++)
      for (int rr = 0; rr < 4; rr++) {
        int mj = m0 + i * 16 + q * 4 + rr;
        int nk = n0 + j * 16 + r;
        if (mj < 208 && nk < KP)
          Gp[((size_t)(mj >> 4) * 7 + (nk >> 5)) * 512 +
             ((mj & 15) + 16 * ((nk >> 3) & 3)) * 8 + (nk & 7)] = f2bf(acc[i][j][rr]);
      }
}

// ---- fused diffuse+conv (unchanged from round 4: 62 us, known-good) --------
#define AG 17920            // A-stage base (u16); G region is [0, 17920)
__global__ __launch_bounds__(512, 4) void k_fused(
    const u16* __restrict__ Gf, const u16* __restrict__ Xf,
    const u16* __restrict__ Wbf, const float* __restrict__ bias,
    float* __restrict__ y) {
  __shared__ __align__(16) u16 lds[AG + 2 * 8192];  // 68,608 B -> 2 blocks/CU
  // bijective XCD swizzle: 3328 blocks, 416/XCD = 2 batches worth
  int id = blockIdx.x;
  int wg = (id & 7) * 416 + (id >> 3);
  int b = wg / 208, rem = wg % 208;
  int jt = rem >> 4, lt = rem & 15;
  int tid = threadIdx.x, wave = tid >> 6, lane = tid & 63;
  int r = lane & 15, q = lane >> 4;
  const u16* Gb = Gf + (size_t)b * 5 * 13 * 7 * 512;
  const u16* Xw = Xf + ((size_t)b * 256 + lt * 16) * 7 * 512;  // 16 tiles

  // stage G: 35 fragment tiles (p*7+ks), each one contiguous 1 KB DMA
  for (int i2 = 0; i2 < 5; i2++) {
    int tile = i2 * 8 + wave;            // wave-uniform
    if (tile < 35) {
      int p = tile / 7, ks = tile - p * 7;
      g2l16(Gb + ((size_t)(p * 13 + jt) * 7 + ks) * 512 + lane * 8,
            &lds[tile * 512 + lane * 8]);
    }
  }
  // prologue: stage ks=0 into buf0 (wave-private tiles wave*2+{0,1})
  for (int i2 = 0; i2 < 2; i2++) {
    int tl = wave * 2 + i2;
    g2l16(Xw + (size_t)tl * 7 * 512 + lane * 8, &lds[AG + tl * 512 + lane * 8]);
  }
  asm volatile("s_waitcnt vmcnt(2)" ::: "memory");  // G landed; stage0 in flight
  __builtin_amdgcn_s_barrier();                     // G visible to all waves

  f32x4 acc1[5][2] = {};
#pragma unroll
  for (int ks = 0; ks < 7; ks++) {
    int cur = ks & 1;
    if (ks < 6) {                      // stage ks+1 into other buffer
      for (int i2 = 0; i2 < 2; i2++) {
        int tl = wave * 2 + i2;
        g2l16(Xw + ((size_t)tl * 7 + ks + 1) * 512 + lane * 8,
              &lds[AG + (cur ^ 1) * 8192 + tl * 512 + lane * 8]);
      }
      asm volatile("s_waitcnt vmcnt(2)" ::: "memory");  // buf[cur] ready (mine)
    } else {
      asm volatile("s_waitcnt vmcnt(0)" ::: "memory");
    }
    bf16x8 af0 = *(const bf16x8*)&lds[AG + cur * 8192 + (wave * 2 + 0) * 512 + lane * 8];
    bf16x8 af1 = *(const bf16x8*)&lds[AG + cur * 8192 + (wave * 2 + 1) * 512 + lane * 8];
    __builtin_amdgcn_s_setprio(1);
#pragma unroll
    for (int p = 0; p < 5; p++) {
      bf16x8 bg = *(const bf16x8*)&lds[(p * 7 + ks) * 512 + lane * 8];
      acc1[p][0] = __builtin_amdgcn_mfma_f32_16x16x32_bf16(af0, bg, acc1[p][0], 0, 0, 0);
      acc1[p][1] = __builtin_amdgcn_mfma_f32_16x16x32_bf16(af1, bg, acc1[p][1], 0, 0, 0);
    }
    __builtin_amdgcn_s_setprio(0);
  }
  __syncthreads();   // all waves done with G + A-stage; reuse LDS for T

  // write T[p][j][t][c] (stride 72 u16, 16B-aligned rows; c XOR-swizzle by j)
#pragma unroll
  for (int p = 0; p < 5; p++)
#pragma unroll
    for (int mf = 0; mf < 2; mf++) {
      int m = (wave * 2 + mf) * 16 + q * 4;
      int tt = m >> 6, c = m & 63;
      int cs = c ^ ((r & 7) << 3);
      int idxT = ((p * 16 + r) * 4 + tt) * 72 + cs;
      u16 v0 = f2bf(acc1[p][mf][0]), v1 = f2bf(acc1[p][mf][1]);
      u16 v2 = f2bf(acc1[p][mf][2]), v3 = f2bf(acc1[p][mf][3]);
      *(uint2*)&lds[idxT] = make_uint2((unsigned)v0 | ((unsigned)v1 << 16),
                                       (unsigned)v2 | ((unsigned)v3 << 16));
    }
  // prefetch all W fragments to VGPRs (contiguous from Wf); fly across barrier
  int mo = wave >> 1, nh = (wave & 1) * 2;
  const u16* Wt = Wbf + (size_t)mo * 10 * 512 + lane * 8;
  bf16x8 aw[10];
#pragma unroll
  for (int ks = 0; ks < 10; ks++) aw[ks] = *(const bf16x8*)(Wt + ks * 512);
  __syncthreads();

  // GEMM-2: y tile 64(o) x 64(j,t), K=320=(p,c). No barriers.
  f32x4 acc2[2] = {};
#pragma unroll
  for (int ks = 0; ks < 10; ks++) {
    int p = ks >> 1, c0 = (ks & 1) * 32;
#pragma unroll
    for (int nf = 0; nf < 2; nf++) {
      int n = (nh + nf) * 16 + r;
      int j = n >> 2, tt = n & 3;
      int cs = (c0 + q * 8) ^ ((j & 7) << 3);
      bf16x8 bt = *(const bf16x8*)&lds[((p * 16 + j) * 4 + tt) * 72 + cs];
      acc2[nf] = __builtin_amdgcn_mfma_f32_16x16x32_bf16(aw[ks], bt, acc2[nf], 0, 0, 0);
    }
  }

  // epilogue: per (o, j) the 4 t-values are 16B-contiguous in y
  int o0 = mo * 16 + q * 4;
  float4 bv = *(const float4*)&bias[o0];
  float* yb = y + (size_t)b * 64 * NKL;
#pragma unroll
  for (int nf = 0; nf < 2; nf++) {
    int n = (nh + nf) * 16 + r;
    int j = n >> 2, tt = n & 3;
    int jnode = jt * 16 + j;
    if (jnode < NK) {
      int col = jnode * 64 + lt * 4 + tt;
      yb[(size_t)(o0 + 0) * NKL + col] = acc2[nf][0] + bv.x;
      yb[(size_t)(o0 + 1) * NKL + col] = acc2[nf][1] + bv.y;
      yb[(size_t)(o0 + 2) * NKL + col] = acc2[nf][2] + bv.z;
      yb[(size_t)(o0 + 3) * NKL + col] = acc2[nf][3] + bv.w;
    }
  }
}

extern "C" void kernel_launch(void* const* d_in, const int* in_sizes, int n_in,
                              void* d_out, int out_size, void* d_ws, size_t ws_size,
                              hipStream_t stream) {
  const float* x = (const float*)d_in[0];
  const float* a0 = (const float*)d_in[1];
  const float* a1 = (const float*)d_in[2];
  const float* W = (const float*)d_in[3];
  const float* bias = (const float*)d_in[4];
  float* y = (float*)d_out;
  char* ws = (char*)d_ws;

  size_t off = 0;
  auto alloc = [&](size_t bytes) {
    size_t o = off;
    off = (off + bytes + 511) & ~(size_t)511;
    return o;
  };
  size_t o_Xf = alloc((size_t)NB * 256 * 7 * 512 * 2);       // 29.4 MB
  size_t o_Gf = alloc((size_t)NB * 5 * 13 * 7 * 512 * 2);    // 7.5 MB
  size_t o_Af = alloc((size_t)NB * 2 * 16 * 7 * 512 * 2);    // 3.7 MB
  size_t o_At = alloc((size_t)NB * 2 * 16 * 7 * 512 * 2);    // 3.7 MB
  size_t o_Wf = alloc((size_t)4 * 10 * 512 * 2);             // 40 KB
  (void)ws_size;

  u16* Xf  = (u16*)(ws + o_Xf);
  u16* Gf  = (u16*)(ws + o_Gf);
  u16* Af  = (u16*)(ws + o_Af);
  u16* Atf = (u16*)(ws + o_At);
  u16* Wf  = (u16*)(ws + o_Wf);

  k_prep<<<dim3(1057), 256, 0, stream>>>(x, a0, a1, W, Xf, Af, Atf, Gf, Wf);
  k_asq<<<dim3(4, 4, 32), 256, 0, stream>>>(Af, Atf, Gf);
  k_fused<<<dim3(16 * 13 * 16), 512, 0, stream>>>(Gf, Xf, Wf, bias, y);
}